// Round 18
// baseline (784.468 us; speedup 1.0000x reference)
//
#include <hip/hip_runtime.h>
#include <cmath>

#define HIDDEN 256
#define NUM_REL 6
#define KA 1536        // A panel K (6 relations * 256)
#define KB 1792        // total K (KA + root block 256)
#define NK64 28        // KB / 64
#define NKA64 24       // KA / 64
#define CTSTRIDE 28672 // halves per 16-col tile of BTf = KB*16

typedef float f32x4_t __attribute__((ext_vector_type(4)));
typedef short bf16x8_t __attribute__((ext_vector_type(8)));

__device__ __forceinline__ float bf2f(ushort u) {
  return __uint_as_float(((uint)u) << 16);
}
__device__ __forceinline__ ushort f2bf(float f) {
  uint u = __float_as_uint(f);
  u += 0x7FFFu + ((u >> 16) & 1u);
  return (ushort)(u >> 16);
}

// ------- fused weight prep: W element + gatevec reduce + BTf store ----------
__global__ __launch_bounds__(256) void prep_weights(
    const float* __restrict__ att, const float* __restrict__ basis,
    const float* __restrict__ root, const float* __restrict__ gw,
    ushort* __restrict__ BTf, float* __restrict__ gatevec) {
  const int d = blockIdx.x, r = blockIdx.y, o = threadIdx.x;
  float v;
  if (r < 6) {
    float s = 0.f;
#pragma unroll
    for (int b = 0; b < 30; ++b)
      s += att[r * 30 + b] * basis[(size_t)b * 65536 + d * 256 + o];
    v = s;
  } else {
    v = root[d * 256 + o];
  }
  const int gk = r * 256 + d;
  BTf[(size_t)(o >> 4) * CTSTRIDE + (gk >> 3) * 128 + (o & 15) * 8 +
      (gk & 7)] = f2bf(v);
  if (r < 6) {
    float t = v * gw[o];
#pragma unroll
    for (int off = 32; off; off >>= 1) t += __shfl_xor(t, off);
    __shared__ float sums[4];
    if ((o & 63) == 0) sums[o >> 6] = t;
    __syncthreads();
    if (o == 0) gatevec[r * 256 + d] = sums[0] + sums[1] + sums[2] + sums[3];
  }
}

// ------- G[r][n] = sigmoid(x[n].gatevec[r] + gb); optional f32->bf16 cvt ----
__global__ __launch_bounds__(256) void gdot_kernel(
    const void* __restrict__ xin, int xIsF32, ushort* __restrict__ xbOut,
    const float* __restrict__ gatevec, const float* __restrict__ gate_b,
    float* __restrict__ G, int N) {
  const int wave = (blockIdx.x * blockDim.x + threadIdx.x) >> 6;
  if (wave >= N) return;
  const int l = threadIdx.x & 63;
  float x0, x1, x2, x3;
  if (xIsF32) {
    float4 xv = ((const float4*)xin)[(size_t)wave * 64 + l];
    x0 = xv.x; x1 = xv.y; x2 = xv.z; x3 = xv.w;
    ushort4 o;
    o.x = f2bf(x0); o.y = f2bf(x1); o.z = f2bf(x2); o.w = f2bf(x3);
    ((ushort4*)xbOut)[(size_t)wave * 64 + l] = o;
  } else {
    ushort4 xv = ((const ushort4*)xin)[(size_t)wave * 64 + l];
    x0 = bf2f(xv.x); x1 = bf2f(xv.y); x2 = bf2f(xv.z); x3 = bf2f(xv.w);
  }
  float out = 0.f;
#pragma unroll
  for (int r = 0; r < NUM_REL; ++r) {
    float4 gv = ((const float4*)(gatevec + r * 256))[l];
    float d = x0 * gv.x + x1 * gv.y + x2 * gv.z + x3 * gv.w;
#pragma unroll
    for (int off = 32; off; off >>= 1) d += __shfl_xor(d, off);
    if (l == r) out = d;
  }
  if (l < NUM_REL) {
    const float gb = gate_b[0];
    G[(size_t)l * N + wave] = 1.f / (1.f + __expf(-(out + gb)));
  }
}

// ------- edge aggregation (round-16 proven) + degree-descending order -------
#define ACCUM(rj, gj, vj)                                                  \
  do {                                                                    \
    const float fx = (gj)*bf2f((vj).x), fy = (gj)*bf2f((vj).y);           \
    const float fz = (gj)*bf2f((vj).z), fw = (gj)*bf2f((vj).w);           \
    switch (rj) {                                                         \
      case 0: a0x += fx; a0y += fy; a0z += fz; a0w += fw; break;          \
      case 1: a1x += fx; a1y += fy; a1z += fz; a1w += fw; break;          \
      case 2: a2x += fx; a2y += fy; a2z += fz; a2w += fw; break;          \
      case 3: a3x += fx; a3y += fy; a3z += fz; a3w += fw; break;          \
      case 4: a4x += fx; a4y += fy; a4z += fz; a4w += fw; break;          \
      default: a5x += fx; a5y += fy; a5z += fz; a5w += fw; break;         \
    }                                                                     \
  } while (0)

#define RELOF(ei) ((ei >= b1) + (ei >= b2) + (ei >= b3) + (ei >= b4) + (ei >= b5))

__global__ __launch_bounds__(256) void edge_agg(
    const ushort* __restrict__ xb, const float* __restrict__ G,
    const int* __restrict__ rp8, const int* __restrict__ src_s,
    const int* __restrict__ perm, ushort* __restrict__ A, int N) {
  const int wid = (blockIdx.x * blockDim.x + threadIdx.x) >> 6;
  if (wid >= N) return;
  const int n = perm[wid];
  const int l = threadIdx.x & 63;
  const int b0 = rp8[n * 8 + 0], b1 = rp8[n * 8 + 1], b2 = rp8[n * 8 + 2];
  const int b3 = rp8[n * 8 + 3], b4 = rp8[n * 8 + 4], b5 = rp8[n * 8 + 5];
  const int b6 = rp8[n * 8 + 6];

  float a0x = 0, a0y = 0, a0z = 0, a0w = 0, a1x = 0, a1y = 0, a1z = 0, a1w = 0;
  float a2x = 0, a2y = 0, a2z = 0, a2w = 0, a3x = 0, a3y = 0, a3z = 0, a3w = 0;
  float a4x = 0, a4y = 0, a4z = 0, a4w = 0, a5x = 0, a5y = 0, a5z = 0, a5w = 0;

  int e = b0;
  for (; e + 7 < b6; e += 8) {
    const int s0 = src_s[e + 0], s1 = src_s[e + 1];
    const int s2 = src_s[e + 2], s3 = src_s[e + 3];
    const int s4 = src_s[e + 4], s5 = src_s[e + 5];
    const int s6 = src_s[e + 6], s7 = src_s[e + 7];
    const ushort4 v0 = ((const ushort4*)(xb + (size_t)s0 * 256))[l];
    const ushort4 v1 = ((const ushort4*)(xb + (size_t)s1 * 256))[l];
    const ushort4 v2 = ((const ushort4*)(xb + (size_t)s2 * 256))[l];
    const ushort4 v3 = ((const ushort4*)(xb + (size_t)s3 * 256))[l];
    const ushort4 v4 = ((const ushort4*)(xb + (size_t)s4 * 256))[l];
    const ushort4 v5 = ((const ushort4*)(xb + (size_t)s5 * 256))[l];
    const ushort4 v6 = ((const ushort4*)(xb + (size_t)s6 * 256))[l];
    const ushort4 v7 = ((const ushort4*)(xb + (size_t)s7 * 256))[l];
    const int r0 = RELOF(e + 0), r1 = RELOF(e + 1), r2 = RELOF(e + 2),
              r3 = RELOF(e + 3), r4 = RELOF(e + 4), r5 = RELOF(e + 5),
              r6 = RELOF(e + 6), r7 = RELOF(e + 7);
    const float g0 = G[(size_t)r0 * N + s0], g1 = G[(size_t)r1 * N + s1];
    const float g2 = G[(size_t)r2 * N + s2], g3 = G[(size_t)r3 * N + s3];
    const float g4 = G[(size_t)r4 * N + s4], g5 = G[(size_t)r5 * N + s5];
    const float g6 = G[(size_t)r6 * N + s6], g7 = G[(size_t)r7 * N + s7];
    ACCUM(r0, g0, v0); ACCUM(r1, g1, v1); ACCUM(r2, g2, v2); ACCUM(r3, g3, v3);
    ACCUM(r4, g4, v4); ACCUM(r5, g5, v5); ACCUM(r6, g6, v6); ACCUM(r7, g7, v7);
  }
  for (; e < b6; ++e) {
    const int s0 = src_s[e];
    const ushort4 v0 = ((const ushort4*)(xb + (size_t)s0 * 256))[l];
    const int r0 = RELOF(e);
    const float g0 = G[(size_t)r0 * N + s0];
    ACCUM(r0, g0, v0);
  }

  const float inv = 1.f / fmaxf((float)(b6 - b0), 1.f);
  ushort* Arow = A + (size_t)n * KA;
  ushort4 o;
  o.x = f2bf(a0x * inv); o.y = f2bf(a0y * inv); o.z = f2bf(a0z * inv); o.w = f2bf(a0w * inv);
  ((ushort4*)(Arow + 0 * 256))[l] = o;
  o.x = f2bf(a1x * inv); o.y = f2bf(a1y * inv); o.z = f2bf(a1z * inv); o.w = f2bf(a1w * inv);
  ((ushort4*)(Arow + 1 * 256))[l] = o;
  o.x = f2bf(a2x * inv); o.y = f2bf(a2y * inv); o.z = f2bf(a2z * inv); o.w = f2bf(a2w * inv);
  ((ushort4*)(Arow + 2 * 256))[l] = o;
  o.x = f2bf(a3x * inv); o.y = f2bf(a3y * inv); o.z = f2bf(a3z * inv); o.w = f2bf(a3w * inv);
  ((ushort4*)(Arow + 3 * 256))[l] = o;
  o.x = f2bf(a4x * inv); o.y = f2bf(a4y * inv); o.z = f2bf(a4z * inv); o.w = f2bf(a4w * inv);
  ((ushort4*)(Arow + 4 * 256))[l] = o;
  o.x = f2bf(a5x * inv); o.y = f2bf(a5y * inv); o.z = f2bf(a5z * inv); o.w = f2bf(a5w * inv);
  ((ushort4*)(Arow + 5 * 256))[l] = o;
}

// ------- bf16 MFMA GEMM v7 (round-16 proven): 64x256 tile, K-step 64 --------
__global__ __launch_bounds__(256) void gemm_fused(
    const ushort* __restrict__ A, const ushort* __restrict__ xb,
    const ushort* __restrict__ BTf, const float* __restrict__ bias,
    void* __restrict__ outPtr, int M, int mode) {
  __shared__ ushort As[3][64 * 64];   // 3 x 8 KB
  const int row0 = blockIdx.x * 64;
  const int tid = threadIdx.x;
  const int w = tid >> 6, l = tid & 63;

  const int srow0 = tid >> 3;              // 0..31
  const int gc = (tid & 7) ^ (srow0 & 7);  // pre-swizzled global chunk
  const int ga0 = min(row0 + srow0, M - 1);
  const int ga1 = min(row0 + 32 + srow0, M - 1);
  const ushort* gpA0 = A + (size_t)ga0 * KA + gc * 8;
  const ushort* gpA1 = A + (size_t)ga1 * KA + gc * 8;
  const ushort* gpX0 = xb + (size_t)ga0 * 256 + gc * 8;
  const ushort* gpX1 = xb + (size_t)ga1 * 256 + gc * 8;

  const ushort* Bb =
      BTf + (size_t)(w * 4) * CTSTRIDE + (l >> 4) * 128 + (l & 15) * 8;

  f32x4_t acc[4][4] = {};

  auto stage = [&](int k, int buf) {
    const int ko = k * 64;
    const ushort* g0 = (k < NKA64) ? (gpA0 + ko) : (gpX0 + (ko - KA));
    const ushort* g1 = (k < NKA64) ? (gpA1 + ko) : (gpX1 + (ko - KA));
    __builtin_amdgcn_global_load_lds(
        (const __attribute__((address_space(1))) void*)g0,
        (__attribute__((address_space(3))) void*)(&As[buf][(size_t)tid * 8]),
        16, 0, 0);
    __builtin_amdgcn_global_load_lds(
        (const __attribute__((address_space(1))) void*)g1,
        (__attribute__((address_space(3))) void*)(&As[buf][(size_t)(256 + tid) * 8]),
        16, 0, 0);
  };

  auto compute = [&](int buf, const bf16x8_t (*b)[4]) {
#pragma unroll
    for (int ks = 0; ks < 2; ++ks) {
      bf16x8_t a[4];
#pragma unroll
      for (int m = 0; m < 4; ++m) {
        const int rr = m * 16 + (l & 15);
        const int s = (ks * 4 + (l >> 4)) ^ (rr & 7);
        a[m] = *(const bf16x8_t*)(&As[buf][rr * 64 + s * 8]);
      }
#pragma unroll
      for (int m = 0; m < 4; ++m)
#pragma unroll
        for (int n = 0; n < 4; ++n)
          acc[m][n] = __builtin_amdgcn_mfma_f32_16x16x32_bf16(
              a[m], b[ks][n], acc[m][n], 0, 0, 0);
    }
  };

  bf16x8_t bE[2][4], bO[2][4];
  stage(0, 0);
  stage(1, 1);
#pragma unroll
  for (int ks = 0; ks < 2; ++ks)
#pragma unroll
    for (int n = 0; n < 4; ++n)
      bE[ks][n] = *(const bf16x8_t*)(Bb + (size_t)n * CTSTRIDE + ks * 512);

  for (int k = 0; k < NK64; k += 2) {
    asm volatile("s_waitcnt vmcnt(10)" ::: "memory");
    __builtin_amdgcn_s_barrier();
#pragma unroll
    for (int ks = 0; ks < 2; ++ks)
#pragma unroll
      for (int n = 0; n < 4; ++n)
        bO[ks][n] = *(const bf16x8_t*)(Bb + (size_t)n * CTSTRIDE +
                                       (size_t)(k + 1) * 1024 + ks * 512);
    if (k + 2 < NK64) stage(k + 2, (k + 2) % 3);
    compute(k % 3, bE);

    asm volatile("s_waitcnt vmcnt(10)" ::: "memory");
    __builtin_amdgcn_s_barrier();
    if (k + 2 < NK64) {
#pragma unroll
      for (int ks = 0; ks < 2; ++ks)
#pragma unroll
        for (int n = 0; n < 4; ++n)
          bE[ks][n] = *(const bf16x8_t*)(Bb + (size_t)n * CTSTRIDE +
                                         (size_t)(k + 2) * 1024 + ks * 512);
    }
    if (k + 3 < NK64) stage(k + 3, (k + 3) % 3);
    compute((k + 1) % 3, bO);
  }

  const int rbase = row0 + (l >> 4) * 4;
  const int cbase = w * 64 + (l & 15);
#pragma unroll
  for (int n = 0; n < 4; ++n) {
    const int col = cbase + n * 16;
    const float bv = bias[col];
#pragma unroll
    for (int m = 0; m < 4; ++m)
#pragma unroll
      for (int i = 0; i < 4; ++i) {
        const int row = rbase + m * 16 + i;
        if (row < M) {
          float v = acc[m][n][i] + bv;
          if (mode == 0) {
            v = fmaxf(v, 0.f);
            ((ushort*)outPtr)[(size_t)row * 256 + col] = f2bf(v);
          } else {
            ((float*)outPtr)[(size_t)row * 256 + col] = v;
          }
        }
      }
  }
}

// ------- CSR build (dst-major bins: dst*8 + rel), atomic-free scatter -------
__global__ void hist_kernel(const int* __restrict__ dst,
                            const int* __restrict__ ety,
                            int* __restrict__ cnt, int* __restrict__ erank,
                            int E) {
  int stride = gridDim.x * blockDim.x;
  for (int e = blockIdx.x * blockDim.x + threadIdx.x; e < E; e += stride)
    erank[e] = atomicAdd(&cnt[dst[e] * 8 + ety[e]], 1);
}

__global__ void scan_reduce(const int* __restrict__ cnt,
                            int* __restrict__ blockSums, int n) {
  __shared__ int sd[256];
  int base = blockIdx.x * 1024;
  int t = threadIdx.x;
  int s = 0;
#pragma unroll
  for (int i = 0; i < 4; ++i) {
    int idx = base + t * 4 + i;
    s += (idx < n) ? cnt[idx] : 0;
  }
  sd[t] = s; __syncthreads();
  for (int off = 128; off; off >>= 1) {
    if (t < off) sd[t] += sd[t + off];
    __syncthreads();
  }
  if (t == 0) blockSums[blockIdx.x] = sd[0];
}

__global__ void scan_offsets(int* __restrict__ blockSums, int nb) {
  __shared__ int sd[512];
  const int t = threadIdx.x;
  const int v = (t < nb) ? blockSums[t] : 0;
  sd[t] = v; __syncthreads();
  for (int off = 1; off < 512; off <<= 1) {
    int u = (t >= off) ? sd[t - off] : 0;
    __syncthreads();
    sd[t] += u;
    __syncthreads();
  }
  if (t < nb) blockSums[t] = sd[t] - v;
}

__global__ void scan_write(const int* __restrict__ cnt,
                           const int* __restrict__ blockSums,
                           int* __restrict__ row_ptr, int n) {
  __shared__ int sd[256];
  int base = blockIdx.x * 1024;
  int t = threadIdx.x;
  int v[4]; int s = 0;
#pragma unroll
  for (int i = 0; i < 4; ++i) {
    int idx = base + t * 4 + i;
    v[i] = (idx < n) ? cnt[idx] : 0;
    s += v[i];
  }
  sd[t] = s; __syncthreads();
  for (int off = 1; off < 256; off <<= 1) {
    int val = (t >= off) ? sd[t - off] : 0;
    __syncthreads();
    sd[t] += val;
    __syncthreads();
  }
  int excl = blockSums[blockIdx.x] + sd[t] - s;
  for (int i = 0; i < 4; ++i) {
    int idx = base + t * 4 + i;
    if (idx < n) {
      row_ptr[idx] = excl;
      excl += v[i];
      if (idx == n - 1) row_ptr[n] = excl;
    }
  }
}

__global__ void scatter_kernel(const int* __restrict__ src,
                               const int* __restrict__ dst,
                               const int* __restrict__ ety,
                               const int* __restrict__ row_ptr,
                               const int* __restrict__ erank,
                               int* __restrict__ src_s, int E) {
  int e = blockIdx.x * blockDim.x + threadIdx.x;
  if (e >= E) return;
  int bin = dst[e] * 8 + ety[e];
  src_s[row_ptr[bin] + erank[e]] = src[e];
}

// ------- degree-descending node permutation (64-bucket sort) ----------------
__global__ void deg_hist(const int* __restrict__ rp8, int* __restrict__ dcnt,
                         int N) {
  int n = blockIdx.x * blockDim.x + threadIdx.x;
  if (n >= N) return;
  int d = rp8[n * 8 + 6] - rp8[n * 8];
  atomicAdd(&dcnt[63 - min(d, 63)], 1);
}

__global__ void deg_scan(const int* __restrict__ dcnt, int* __restrict__ dcur) {
  if (threadIdx.x == 0) {
    int run = 0;
    for (int i = 0; i < 64; ++i) { dcur[i] = run; run += dcnt[i]; }
  }
}

__global__ void deg_scatter(const int* __restrict__ rp8, int* __restrict__ dcur,
                            int* __restrict__ perm, int N) {
  int n = blockIdx.x * blockDim.x + threadIdx.x;
  if (n >= N) return;
  int d = rp8[n * 8 + 6] - rp8[n * 8];
  int pos = atomicAdd(&dcur[63 - min(d, 63)], 1);
  perm[pos] = n;
}

static inline size_t align16(size_t x) { return (x + 15) & ~(size_t)15; }

extern "C" void kernel_launch(void* const* d_in, const int* in_sizes, int n_in,
                              void* d_out, int out_size, void* d_ws,
                              size_t ws_size, hipStream_t stream) {
  const float* x    = (const float*)d_in[0];
  const int*   src  = (const int*)d_in[1];
  const int*   dst  = (const int*)d_in[2];
  const int*   ety  = (const int*)d_in[3];

  const int N   = in_sizes[0] / HIDDEN;   // 50000
  const int E   = in_sizes[1];            // 800000
  const int RN2 = N * 8;                  // dst-major bins (2 pad rels)

  // ---- workspace layout ----
  char* p = (char*)d_ws;
  ushort* BTf    = (ushort*)p; p += align16(((size_t)16 * CTSTRIDE + 4096) * 2);
  float* gatevec = (float*)p;  p += align16((size_t)NUM_REL * 256 * 4);
  float* G       = (float*)p;  p += align16((size_t)NUM_REL * N * 4);
  ushort* xb0    = (ushort*)p; p += align16((size_t)N * HIDDEN * 2);  // x bf16
  ushort* xb1    = (ushort*)p; p += align16((size_t)N * HIDDEN * 2);  // h bf16
  int* cnt       = (int*)p;    p += align16((size_t)RN2 * 4);
  int* erank     = (int*)p;    p += align16((size_t)E * 4);
  int* row_ptr   = (int*)p;    p += align16((size_t)(RN2 + 1) * 4);
  int* blockSums = (int*)p;    p += 2048;
  int* dbuf      = (int*)p;    p += 1024;            // dcnt[64] + dcur[64]
  int* perm      = (int*)p;    p += align16((size_t)N * 4);
  int* src_s     = (int*)p;    p += align16((size_t)E * 4);
  ushort* A      = (ushort*)p;   // N * KA bf16 = 153.6 MB

  int* dcnt = dbuf;
  int* dcur = dbuf + 64;

  const int scanBlocks = (RN2 + 1023) / 1024;

  // ---- CSR build (shared by both layers) ----
  hipMemsetAsync(cnt, 0, (size_t)RN2 * sizeof(int), stream);
  hipMemsetAsync(dcnt, 0, 64 * sizeof(int), stream);
  hist_kernel<<<2048, 256, 0, stream>>>(dst, ety, cnt, erank, E);
  scan_reduce<<<scanBlocks, 256, 0, stream>>>(cnt, blockSums, RN2);
  scan_offsets<<<1, 512, 0, stream>>>(blockSums, scanBlocks);
  scan_write<<<scanBlocks, 256, 0, stream>>>(cnt, blockSums, row_ptr, RN2);
  scatter_kernel<<<(E + 255) / 256, 256, 0, stream>>>(src, dst, ety, row_ptr,
                                                      erank, src_s, E);
  // degree-descending permutation
  deg_hist<<<(N + 255) / 256, 256, 0, stream>>>(row_ptr, dcnt, N);
  deg_scan<<<1, 64, 0, stream>>>(dcnt, dcur);
  deg_scatter<<<(N + 255) / 256, 256, 0, stream>>>(row_ptr, dcur, perm, N);

  const int nodeBlocks = (N * 64 + 255) / 256;   // wave-per-node launches
  const int gemmGrid = (N + 63) / 64;

  for (int layer = 0; layer < 2; ++layer) {
    const float* bas  = (const float*)d_in[layer ? 10 : 4];
    const float* att  = (const float*)d_in[layer ? 11 : 5];
    const float* root = (const float*)d_in[layer ? 12 : 6];
    const float* bias = (const float*)d_in[layer ? 13 : 7];
    const float* gw   = (const float*)d_in[layer ? 14 : 8];
    const float* gb   = (const float*)d_in[layer ? 15 : 9];
    const ushort* xb  = layer ? xb1 : xb0;
    void* outp = layer ? d_out : (void*)xb1;
    const int mode = layer ? 1 : 0;

    prep_weights<<<dim3(256, 7), 256, 0, stream>>>(att, bas, root, gw, BTf,
                                                   gatevec);
    gdot_kernel<<<nodeBlocks, 256, 0, stream>>>(
        layer ? (const void*)xb1 : (const void*)x, layer ? 0 : 1, xb0,
        gatevec, gb, G, N);
    edge_agg<<<nodeBlocks, 256, 0, stream>>>(xb, G, row_ptr, src_s, perm, A,
                                             N);
    gemm_fused<<<gemmGrid, 256, 0, stream>>>(A, xb, BTf, bias, outp, N, mode);
  }
}

// Round 19
// 482.579 us; speedup vs baseline: 1.6256x; 1.6256x over previous
//
#include <hip/hip_runtime.h>
#include <cmath>

#define HIDDEN 256
#define NUM_REL 6
#define KA 1536        // A panel K (6 relations * 256)
#define KB 1792        // total K (KA + root block 256)
#define NK64 28        // KB / 64
#define NKA64 24       // KA / 64
#define CTSTRIDE 28672 // halves per 16-col tile of BTf = KB*16

typedef float f32x4_t __attribute__((ext_vector_type(4)));
typedef short bf16x8_t __attribute__((ext_vector_type(8)));

__device__ __forceinline__ float bf2f(ushort u) {
  return __uint_as_float(((uint)u) << 16);
}
__device__ __forceinline__ ushort f2bf(float f) {
  uint u = __float_as_uint(f);
  u += 0x7FFFu + ((u >> 16) & 1u);
  return (ushort)(u >> 16);
}

// ------- fused weight prep: W element + gatevec reduce + BTf store ----------
__global__ __launch_bounds__(256) void prep_weights(
    const float* __restrict__ att, const float* __restrict__ basis,
    const float* __restrict__ root, const float* __restrict__ gw,
    ushort* __restrict__ BTf, float* __restrict__ gatevec) {
  const int d = blockIdx.x, r = blockIdx.y, o = threadIdx.x;
  float v;
  if (r < 6) {
    float s = 0.f;
#pragma unroll
    for (int b = 0; b < 30; ++b)
      s += att[r * 30 + b] * basis[(size_t)b * 65536 + d * 256 + o];
    v = s;
  } else {
    v = root[d * 256 + o];
  }
  const int gk = r * 256 + d;
  BTf[(size_t)(o >> 4) * CTSTRIDE + (gk >> 3) * 128 + (o & 15) * 8 +
      (gk & 7)] = f2bf(v);
  if (r < 6) {
    float t = v * gw[o];
#pragma unroll
    for (int off = 32; off; off >>= 1) t += __shfl_xor(t, off);
    __shared__ float sums[4];
    if ((o & 63) == 0) sums[o >> 6] = t;
    __syncthreads();
    if (o == 0) gatevec[r * 256 + d] = sums[0] + sums[1] + sums[2] + sums[3];
  }
}

// ------- G[r][n] = sigmoid(x[n].gatevec[r] + gb); optional f32->bf16 cvt ----
__global__ __launch_bounds__(256) void gdot_kernel(
    const void* __restrict__ xin, int xIsF32, ushort* __restrict__ xbOut,
    const float* __restrict__ gatevec, const float* __restrict__ gate_b,
    float* __restrict__ G, int N) {
  const int wave = (blockIdx.x * blockDim.x + threadIdx.x) >> 6;
  if (wave >= N) return;
  const int l = threadIdx.x & 63;
  float x0, x1, x2, x3;
  if (xIsF32) {
    float4 xv = ((const float4*)xin)[(size_t)wave * 64 + l];
    x0 = xv.x; x1 = xv.y; x2 = xv.z; x3 = xv.w;
    ushort4 o;
    o.x = f2bf(x0); o.y = f2bf(x1); o.z = f2bf(x2); o.w = f2bf(x3);
    ((ushort4*)xbOut)[(size_t)wave * 64 + l] = o;
  } else {
    ushort4 xv = ((const ushort4*)xin)[(size_t)wave * 64 + l];
    x0 = bf2f(xv.x); x1 = bf2f(xv.y); x2 = bf2f(xv.z); x3 = bf2f(xv.w);
  }
  float out = 0.f;
#pragma unroll
  for (int r = 0; r < NUM_REL; ++r) {
    float4 gv = ((const float4*)(gatevec + r * 256))[l];
    float d = x0 * gv.x + x1 * gv.y + x2 * gv.z + x3 * gv.w;
#pragma unroll
    for (int off = 32; off; off >>= 1) d += __shfl_xor(d, off);
    if (l == r) out = d;
  }
  if (l < NUM_REL) {
    const float gb = gate_b[0];
    G[(size_t)l * N + wave] = 1.f / (1.f + __expf(-(out + gb)));
  }
}

// ------- edge aggregation (round-14 proven): one wave per dst node ----------
#define ACCUM(rj, gj, vj)                                                  \
  do {                                                                    \
    const float fx = (gj)*bf2f((vj).x), fy = (gj)*bf2f((vj).y);           \
    const float fz = (gj)*bf2f((vj).z), fw = (gj)*bf2f((vj).w);           \
    switch (rj) {                                                         \
      case 0: a0x += fx; a0y += fy; a0z += fz; a0w += fw; break;          \
      case 1: a1x += fx; a1y += fy; a1z += fz; a1w += fw; break;          \
      case 2: a2x += fx; a2y += fy; a2z += fz; a2w += fw; break;          \
      case 3: a3x += fx; a3y += fy; a3z += fz; a3w += fw; break;          \
      case 4: a4x += fx; a4y += fy; a4z += fz; a4w += fw; break;          \
      default: a5x += fx; a5y += fy; a5z += fz; a5w += fw; break;         \
    }                                                                     \
  } while (0)

#define RELOF(ei) ((ei >= b1) + (ei >= b2) + (ei >= b3) + (ei >= b4) + (ei >= b5))

__global__ __launch_bounds__(256) void edge_agg(
    const ushort* __restrict__ xb, const float* __restrict__ G,
    const int* __restrict__ rp8, const int* __restrict__ src_s,
    ushort* __restrict__ A, int N) {
  const int n = (blockIdx.x * blockDim.x + threadIdx.x) >> 6;
  if (n >= N) return;
  const int l = threadIdx.x & 63;
  const int b0 = rp8[n * 8 + 0], b1 = rp8[n * 8 + 1], b2 = rp8[n * 8 + 2];
  const int b3 = rp8[n * 8 + 3], b4 = rp8[n * 8 + 4], b5 = rp8[n * 8 + 5];
  const int b6 = rp8[n * 8 + 6];

  float a0x = 0, a0y = 0, a0z = 0, a0w = 0, a1x = 0, a1y = 0, a1z = 0, a1w = 0;
  float a2x = 0, a2y = 0, a2z = 0, a2w = 0, a3x = 0, a3y = 0, a3z = 0, a3w = 0;
  float a4x = 0, a4y = 0, a4z = 0, a4w = 0, a5x = 0, a5y = 0, a5z = 0, a5w = 0;

  int e = b0;
  for (; e + 7 < b6; e += 8) {
    const int s0 = src_s[e + 0], s1 = src_s[e + 1];
    const int s2 = src_s[e + 2], s3 = src_s[e + 3];
    const int s4 = src_s[e + 4], s5 = src_s[e + 5];
    const int s6 = src_s[e + 6], s7 = src_s[e + 7];
    const ushort4 v0 = ((const ushort4*)(xb + (size_t)s0 * 256))[l];
    const ushort4 v1 = ((const ushort4*)(xb + (size_t)s1 * 256))[l];
    const ushort4 v2 = ((const ushort4*)(xb + (size_t)s2 * 256))[l];
    const ushort4 v3 = ((const ushort4*)(xb + (size_t)s3 * 256))[l];
    const ushort4 v4 = ((const ushort4*)(xb + (size_t)s4 * 256))[l];
    const ushort4 v5 = ((const ushort4*)(xb + (size_t)s5 * 256))[l];
    const ushort4 v6 = ((const ushort4*)(xb + (size_t)s6 * 256))[l];
    const ushort4 v7 = ((const ushort4*)(xb + (size_t)s7 * 256))[l];
    const int r0 = RELOF(e + 0), r1 = RELOF(e + 1), r2 = RELOF(e + 2),
              r3 = RELOF(e + 3), r4 = RELOF(e + 4), r5 = RELOF(e + 5),
              r6 = RELOF(e + 6), r7 = RELOF(e + 7);
    const float g0 = G[(size_t)r0 * N + s0], g1 = G[(size_t)r1 * N + s1];
    const float g2 = G[(size_t)r2 * N + s2], g3 = G[(size_t)r3 * N + s3];
    const float g4 = G[(size_t)r4 * N + s4], g5 = G[(size_t)r5 * N + s5];
    const float g6 = G[(size_t)r6 * N + s6], g7 = G[(size_t)r7 * N + s7];
    ACCUM(r0, g0, v0); ACCUM(r1, g1, v1); ACCUM(r2, g2, v2); ACCUM(r3, g3, v3);
    ACCUM(r4, g4, v4); ACCUM(r5, g5, v5); ACCUM(r6, g6, v6); ACCUM(r7, g7, v7);
  }
  for (; e < b6; ++e) {
    const int s0 = src_s[e];
    const ushort4 v0 = ((const ushort4*)(xb + (size_t)s0 * 256))[l];
    const int r0 = RELOF(e);
    const float g0 = G[(size_t)r0 * N + s0];
    ACCUM(r0, g0, v0);
  }

  const float inv = 1.f / fmaxf((float)(b6 - b0), 1.f);
  ushort* Arow = A + (size_t)n * KA;
  ushort4 o;
  o.x = f2bf(a0x * inv); o.y = f2bf(a0y * inv); o.z = f2bf(a0z * inv); o.w = f2bf(a0w * inv);
  ((ushort4*)(Arow + 0 * 256))[l] = o;
  o.x = f2bf(a1x * inv); o.y = f2bf(a1y * inv); o.z = f2bf(a1z * inv); o.w = f2bf(a1w * inv);
  ((ushort4*)(Arow + 1 * 256))[l] = o;
  o.x = f2bf(a2x * inv); o.y = f2bf(a2y * inv); o.z = f2bf(a2z * inv); o.w = f2bf(a2w * inv);
  ((ushort4*)(Arow + 2 * 256))[l] = o;
  o.x = f2bf(a3x * inv); o.y = f2bf(a3y * inv); o.z = f2bf(a3z * inv); o.w = f2bf(a3w * inv);
  ((ushort4*)(Arow + 3 * 256))[l] = o;
  o.x = f2bf(a4x * inv); o.y = f2bf(a4y * inv); o.z = f2bf(a4z * inv); o.w = f2bf(a4w * inv);
  ((ushort4*)(Arow + 4 * 256))[l] = o;
  o.x = f2bf(a5x * inv); o.y = f2bf(a5y * inv); o.z = f2bf(a5z * inv); o.w = f2bf(a5w * inv);
  ((ushort4*)(Arow + 5 * 256))[l] = o;
}

// ------- bf16 MFMA GEMM v7: 64x256 tile, K-step 64, 2 k-slices/sub-step -----
__global__ __launch_bounds__(256) void gemm_fused(
    const ushort* __restrict__ A, const ushort* __restrict__ xb,
    const ushort* __restrict__ BTf, const float* __restrict__ bias,
    void* __restrict__ outPtr, int M, int mode) {
  __shared__ ushort As[3][64 * 64];   // 3 x 8 KB
  const int row0 = blockIdx.x * 64;
  const int tid = threadIdx.x;
  const int w = tid >> 6, l = tid & 63;

  const int srow0 = tid >> 3;              // 0..31
  const int gc = (tid & 7) ^ (srow0 & 7);  // pre-swizzled global chunk
  const int ga0 = min(row0 + srow0, M - 1);
  const int ga1 = min(row0 + 32 + srow0, M - 1);
  const ushort* gpA0 = A + (size_t)ga0 * KA + gc * 8;
  const ushort* gpA1 = A + (size_t)ga1 * KA + gc * 8;
  const ushort* gpX0 = xb + (size_t)ga0 * 256 + gc * 8;
  const ushort* gpX1 = xb + (size_t)ga1 * 256 + gc * 8;

  const ushort* Bb =
      BTf + (size_t)(w * 4) * CTSTRIDE + (l >> 4) * 128 + (l & 15) * 8;

  f32x4_t acc[4][4] = {};

  auto stage = [&](int k, int buf) {
    const int ko = k * 64;
    const ushort* g0 = (k < NKA64) ? (gpA0 + ko) : (gpX0 + (ko - KA));
    const ushort* g1 = (k < NKA64) ? (gpA1 + ko) : (gpX1 + (ko - KA));
    __builtin_amdgcn_global_load_lds(
        (const __attribute__((address_space(1))) void*)g0,
        (__attribute__((address_space(3))) void*)(&As[buf][(size_t)tid * 8]),
        16, 0, 0);
    __builtin_amdgcn_global_load_lds(
        (const __attribute__((address_space(1))) void*)g1,
        (__attribute__((address_space(3))) void*)(&As[buf][(size_t)(256 + tid) * 8]),
        16, 0, 0);
  };

  auto compute = [&](int buf, const bf16x8_t (*b)[4]) {
#pragma unroll
    for (int ks = 0; ks < 2; ++ks) {
      bf16x8_t a[4];
#pragma unroll
      for (int m = 0; m < 4; ++m) {
        const int rr = m * 16 + (l & 15);
        const int s = (ks * 4 + (l >> 4)) ^ (rr & 7);
        a[m] = *(const bf16x8_t*)(&As[buf][rr * 64 + s * 8]);
      }
#pragma unroll
      for (int m = 0; m < 4; ++m)
#pragma unroll
        for (int n = 0; n < 4; ++n)
          acc[m][n] = __builtin_amdgcn_mfma_f32_16x16x32_bf16(
              a[m], b[ks][n], acc[m][n], 0, 0, 0);
    }
  };

  bf16x8_t bE[2][4], bO[2][4];
  stage(0, 0);
  stage(1, 1);
#pragma unroll
  for (int ks = 0; ks < 2; ++ks)
#pragma unroll
    for (int n = 0; n < 4; ++n)
      bE[ks][n] = *(const bf16x8_t*)(Bb + (size_t)n * CTSTRIDE + ks * 512);

  for (int k = 0; k < NK64; k += 2) {
    asm volatile("s_waitcnt vmcnt(10)" ::: "memory");
    __builtin_amdgcn_s_barrier();
#pragma unroll
    for (int ks = 0; ks < 2; ++ks)
#pragma unroll
      for (int n = 0; n < 4; ++n)
        bO[ks][n] = *(const bf16x8_t*)(Bb + (size_t)n * CTSTRIDE +
                                       (size_t)(k + 1) * 1024 + ks * 512);
    if (k + 2 < NK64) stage(k + 2, (k + 2) % 3);
    compute(k % 3, bE);

    asm volatile("s_waitcnt vmcnt(10)" ::: "memory");
    __builtin_amdgcn_s_barrier();
    if (k + 2 < NK64) {
#pragma unroll
      for (int ks = 0; ks < 2; ++ks)
#pragma unroll
        for (int n = 0; n < 4; ++n)
          bE[ks][n] = *(const bf16x8_t*)(Bb + (size_t)n * CTSTRIDE +
                                         (size_t)(k + 2) * 1024 + ks * 512);
    }
    if (k + 3 < NK64) stage(k + 3, (k + 3) % 3);
    compute((k + 1) % 3, bO);
  }

  const int rbase = row0 + (l >> 4) * 4;
  const int cbase = w * 64 + (l & 15);
#pragma unroll
  for (int n = 0; n < 4; ++n) {
    const int col = cbase + n * 16;
    const float bv = bias[col];
#pragma unroll
    for (int m = 0; m < 4; ++m)
#pragma unroll
      for (int i = 0; i < 4; ++i) {
        const int row = rbase + m * 16 + i;
        if (row < M) {
          float v = acc[m][n][i] + bv;
          if (mode == 0) {
            v = fmaxf(v, 0.f);
            ((ushort*)outPtr)[(size_t)row * 256 + col] = f2bf(v);
          } else {
            ((float*)outPtr)[(size_t)row * 256 + col] = v;
          }
        }
      }
  }
}

// ------- CSR build (dst-major bins: dst*8 + rel), atomic-free scatter -------
__global__ void hist_kernel(const int* __restrict__ dst,
                            const int* __restrict__ ety,
                            int* __restrict__ cnt, int* __restrict__ erank,
                            int E) {
  int stride = gridDim.x * blockDim.x;
  for (int e = blockIdx.x * blockDim.x + threadIdx.x; e < E; e += stride)
    erank[e] = atomicAdd(&cnt[dst[e] * 8 + ety[e]], 1);
}

__global__ void scan_reduce(const int* __restrict__ cnt,
                            int* __restrict__ blockSums, int n) {
  __shared__ int sd[256];
  int base = blockIdx.x * 1024;
  int t = threadIdx.x;
  int s = 0;
#pragma unroll
  for (int i = 0; i < 4; ++i) {
    int idx = base + t * 4 + i;
    s += (idx < n) ? cnt[idx] : 0;
  }
  sd[t] = s; __syncthreads();
  for (int off = 128; off; off >>= 1) {
    if (t < off) sd[t] += sd[t + off];
    __syncthreads();
  }
  if (t == 0) blockSums[blockIdx.x] = sd[0];
}

__global__ void scan_offsets(int* __restrict__ blockSums, int nb) {
  __shared__ int sd[512];
  const int t = threadIdx.x;
  const int v = (t < nb) ? blockSums[t] : 0;
  sd[t] = v; __syncthreads();
  for (int off = 1; off < 512; off <<= 1) {
    int u = (t >= off) ? sd[t - off] : 0;
    __syncthreads();
    sd[t] += u;
    __syncthreads();
  }
  if (t < nb) blockSums[t] = sd[t] - v;
}

__global__ void scan_write(const int* __restrict__ cnt,
                           const int* __restrict__ blockSums,
                           int* __restrict__ row_ptr, int n) {
  __shared__ int sd[256];
  int base = blockIdx.x * 1024;
  int t = threadIdx.x;
  int v[4]; int s = 0;
#pragma unroll
  for (int i = 0; i < 4; ++i) {
    int idx = base + t * 4 + i;
    v[i] = (idx < n) ? cnt[idx] : 0;
    s += v[i];
  }
  sd[t] = s; __syncthreads();
  for (int off = 1; off < 256; off <<= 1) {
    int val = (t >= off) ? sd[t - off] : 0;
    __syncthreads();
    sd[t] += val;
    __syncthreads();
  }
  int excl = blockSums[blockIdx.x] + sd[t] - s;
  for (int i = 0; i < 4; ++i) {
    int idx = base + t * 4 + i;
    if (idx < n) {
      row_ptr[idx] = excl;
      excl += v[i];
      if (idx == n - 1) row_ptr[n] = excl;
    }
  }
}

__global__ void scatter_kernel(const int* __restrict__ src,
                               const int* __restrict__ dst,
                               const int* __restrict__ ety,
                               const int* __restrict__ row_ptr,
                               const int* __restrict__ erank,
                               int* __restrict__ src_s, int E) {
  int stride = gridDim.x * blockDim.x;
  for (int e = blockIdx.x * blockDim.x + threadIdx.x; e < E; e += stride) {
    int bin = dst[e] * 8 + ety[e];
    src_s[row_ptr[bin] + erank[e]] = src[e];
  }
}

static inline size_t align16(size_t x) { return (x + 15) & ~(size_t)15; }

extern "C" void kernel_launch(void* const* d_in, const int* in_sizes, int n_in,
                              void* d_out, int out_size, void* d_ws,
                              size_t ws_size, hipStream_t stream) {
  const float* x    = (const float*)d_in[0];
  const int*   src  = (const int*)d_in[1];
  const int*   dst  = (const int*)d_in[2];
  const int*   ety  = (const int*)d_in[3];

  const int N   = in_sizes[0] / HIDDEN;   // 50000
  const int E   = in_sizes[1];            // 800000
  const int RN2 = N * 8;                  // dst-major bins (2 pad rels)

  // ---- workspace layout ----
  char* p = (char*)d_ws;
  ushort* BTf    = (ushort*)p; p += align16(((size_t)16 * CTSTRIDE + 4096) * 2);
  float* gatevec = (float*)p;  p += align16((size_t)NUM_REL * 256 * 4);
  float* G       = (float*)p;  p += align16((size_t)NUM_REL * N * 4);
  ushort* xb0    = (ushort*)p; p += align16((size_t)N * HIDDEN * 2);  // x bf16
  ushort* xb1    = (ushort*)p; p += align16((size_t)N * HIDDEN * 2);  // h bf16
  int* cnt       = (int*)p;    p += align16((size_t)RN2 * 4);
  int* erank     = (int*)p;    p += align16((size_t)E * 4);
  int* row_ptr   = (int*)p;    p += align16((size_t)(RN2 + 1) * 4);
  int* blockSums = (int*)p;    p += 2048;
  int* src_s     = (int*)p;    p += align16((size_t)E * 4);
  ushort* A      = (ushort*)p;   // N * KA bf16 = 153.6 MB

  const int scanBlocks = (RN2 + 1023) / 1024;

  // ---- CSR build (shared by both layers) ----
  hipMemsetAsync(cnt, 0, (size_t)RN2 * sizeof(int), stream);
  hist_kernel<<<2048, 256, 0, stream>>>(dst, ety, cnt, erank, E);
  scan_reduce<<<scanBlocks, 256, 0, stream>>>(cnt, blockSums, RN2);
  scan_offsets<<<1, 512, 0, stream>>>(blockSums, scanBlocks);
  scan_write<<<scanBlocks, 256, 0, stream>>>(cnt, blockSums, row_ptr, RN2);
  scatter_kernel<<<2048, 256, 0, stream>>>(src, dst, ety, row_ptr, erank,
                                           src_s, E);

  const int nodeBlocks = (N * 64 + 255) / 256;   // wave-per-node launches
  const int gemmGrid = (N + 63) / 64;

  for (int layer = 0; layer < 2; ++layer) {
    const float* bas  = (const float*)d_in[layer ? 10 : 4];
    const float* att  = (const float*)d_in[layer ? 11 : 5];
    const float* root = (const float*)d_in[layer ? 12 : 6];
    const float* bias = (const float*)d_in[layer ? 13 : 7];
    const float* gw   = (const float*)d_in[layer ? 14 : 8];
    const float* gb   = (const float*)d_in[layer ? 15 : 9];
    const ushort* xb  = layer ? xb1 : xb0;
    void* outp = layer ? d_out : (void*)xb1;
    const int mode = layer ? 1 : 0;

    prep_weights<<<dim3(256, 7), 256, 0, stream>>>(att, bas, root, gw, BTf,
                                                   gatevec);
    gdot_kernel<<<nodeBlocks, 256, 0, stream>>>(
        layer ? (const void*)xb1 : (const void*)x, layer ? 0 : 1, xb0,
        gatevec, gb, G, N);
    edge_agg<<<nodeBlocks, 256, 0, stream>>>(xb, G, row_ptr, src_s, A, N);
    gemm_fused<<<gemmGrid, 256, 0, stream>>>(A, xb, BTf, bias, outp, N, mode);
  }
}